// Round 6
// baseline (236.891 us; speedup 1.0000x reference)
//
#include <hip/hip_runtime.h>

#define B_   32
#define S_   2048
#define D_   512
#define H_   32
#define BS_  (B_*S_)
#define INV_SCALE 0.17677669529663689f   // 1/sqrt(32)

// workspace layout (bytes):
// [0, 32768):        PTbf    ushort[32][512]   bf16 transposed projector
// [32768, 65536):    zdm     float2[4096]      per-block (Z, DM) partials
// [65536, 8454144):  partial float[4096][512]  per-block fp32 numerator partials

typedef short  s16x8 __attribute__((ext_vector_type(8)));
typedef float  f32x4 __attribute__((ext_vector_type(4)));

__device__ __forceinline__ float sigmoidf_(float x) {
    return 1.0f / (1.0f + __expf(-x));
}

__device__ __forceinline__ unsigned short f2bf(float f) {
    unsigned u = __float_as_uint(f);
    u += 0x7fffu + ((u >> 16) & 1u);     // round-to-nearest-even
    return (unsigned short)(u >> 16);
}

// ---------------- transpose projector to bf16: PTbf[j][d] = bf16(P[d][j]) ----
__global__ void kTransposeBf(const float* __restrict__ P, unsigned short* __restrict__ PTbf) {
    int o = blockIdx.x * 256 + threadIdx.x;      // 16384 total
    int j = o >> 9, d = o & 511;
    PTbf[o] = f2bf(P[d * H_ + j]);
}

// ---- fused scores + fp32 register-tail weighted partials: 16 rows/block, 128 thr ----
#define XST 520                               // bf16 row stride in LDS (512 + 8 pad)

__global__ __launch_bounds__(128) void kFused(
        const float* __restrict__ inp, const int* __restrict__ mask,
        const unsigned short* __restrict__ PTbf, const float* __restrict__ hd,
        const float* __restrict__ ev,
        float* __restrict__ partial, float2* __restrict__ zdm) {
    __shared__ unsigned short xs[16 * XST];   // 16640 B
    __shared__ float w0f[16 * 33];            // 2112 B
    __shared__ float w1f[16 * 33];            // 2112 B
    __shared__ float cs[16];                  // unnormalized coefficients

    const int tid = threadIdx.x;
    const int blk = blockIdx.x;
    const int rowBase = blk * 16;

    // ---- stage x tile (16 rows x 512 fp32 = 32 KB): thread tid holds
    //      float4-column `tid` for ALL 16 rows (row = i) — kept in registers ----
    const float4* g = (const float4*)inp + (size_t)rowBase * 128;
    float4 tmp[16];
    #pragma unroll
    for (int i = 0; i < 16; ++i)
        tmp[i] = g[i * 128 + tid];
    #pragma unroll
    for (int i = 0; i < 16; ++i) {
        ushort4 u;
        u.x = f2bf(tmp[i].x); u.y = f2bf(tmp[i].y);
        u.z = f2bf(tmp[i].z); u.w = f2bf(tmp[i].w);
        *(ushort4*)(xs + i * XST + tid * 4) = u;   // conflict-free (4 dw/bank min)
    }
    __syncthreads();

    // ---- MFMA: wave ct computes 16x16 tile over cols ct*16..ct*16+15 ----
    const int wave = tid >> 6, lane = tid & 63;
    const int ct = wave;
    const int m = lane & 15, quad = lane >> 4;

    const unsigned short* arow = xs + m * XST + quad * 8;
    const unsigned short* brow = PTbf + (size_t)(ct * 16 + m) * 512 + quad * 8;

    f32x4 acc = {0.f, 0.f, 0.f, 0.f};
    #pragma unroll
    for (int ks = 0; ks < 16; ++ks) {
        s16x8 a = *(const s16x8*)(arow + ks * 32);
        s16x8 b = *(const s16x8*)(brow + ks * 32);
        acc = __builtin_amdgcn_mfma_f32_16x16x32_bf16(a, b, acc, 0, 0, 0);
    }

    // ---- epilogue: sigmoid(mask * score / sqrt(32)); C/D: col=lane&15, row=quad*4+reg ----
    #pragma unroll
    for (int r = 0; r < 4; ++r) {
        int rowL = quad * 4 + r;
        float mr = (mask[rowBase + rowL] != 0) ? 1.0f : 0.0f;
        w0f[rowL * 33 + ct * 16 + m] = sigmoidf_(mr * acc[r] * INV_SCALE);
    }
    __syncthreads();

    // ---- hidden layer: w1[row][k] = sigmoid(sum_j w0[row][j]*hd[j][k] / scale) ----
    {
        const int k = tid & 31, slot = tid >> 5;  // 4 slots x 4 rows
        #pragma unroll
        for (int t = 0; t < 4; ++t) {
            int row = slot + 4 * t;
            float s = 0.f;
            #pragma unroll
            for (int j = 0; j < 32; ++j)
                s = fmaf(w0f[row * 33 + j], hd[j * 32 + k], s);
            w1f[row * 33 + k] = sigmoidf_(s * INV_SCALE);
        }
    }
    __syncthreads();

    // ---- evaluator -> c_s = m*exp(v_s); block (Z, DM) partial via wave 0 ----
    if (tid < 64) {
        float e = 0.f, mm = 0.f;
        if (tid < 16) {
            float s = 0.f;
            #pragma unroll
            for (int k = 0; k < 32; ++k)
                s = fmaf(w1f[tid * 33 + k], ev[k], s);
            float val = sigmoidf_(s * INV_SCALE);    // in (0,1): exp safe, no max-sub
            e  = __expf(val);
            mm = (mask[rowBase + tid] != 0) ? 1.0f : 0.0f;
            cs[tid] = mm * e;
        }
        float z = e, dm = mm * e;                    // zeros beyond lane 15
        #pragma unroll
        for (int o = 32; o > 0; o >>= 1) {
            z  += __shfl_down(z, o);
            dm += __shfl_down(dm, o);
        }
        if (tid == 0) zdm[blk] = make_float2(z, dm);
    }
    __syncthreads();

    // ---- fp32 numerator partial from REGISTERS: col4 = tid, all 16 rows in tmp ----
    float4 a0 = make_float4(0.f, 0.f, 0.f, 0.f);
    #pragma unroll
    for (int i = 0; i < 16; ++i) {
        float c = cs[i];
        a0.x = fmaf(c, tmp[i].x, a0.x);
        a0.y = fmaf(c, tmp[i].y, a0.y);
        a0.z = fmaf(c, tmp[i].z, a0.z);
        a0.w = fmaf(c, tmp[i].w, a0.w);
    }
    ((float4*)partial)[(size_t)blk * 128 + tid] = a0;
}

// ---- reduce 128 partials per b, normalize, write out: block = (b, d-eighth) ----
__global__ __launch_bounds__(256) void kReduce(
        const float* __restrict__ partial, const float2* __restrict__ zdm,
        float* __restrict__ out) {
    const int b = blockIdx.x >> 3, dc = blockIdx.x & 7;   // 64 floats = 16 float4
    const int tid = threadIdx.x;
    const int sg = tid >> 4, dl = tid & 15;               // 16 groups x 16 lanes
    __shared__ float sInv;
    __shared__ float4 red[256];

    if (tid < 64) {
        float2 p0 = zdm[b * 128 + tid];
        float2 p1 = zdm[b * 128 + 64 + tid];
        float z = p0.x + p1.x, dm = p0.y + p1.y;
        #pragma unroll
        for (int o = 32; o > 0; o >>= 1) {
            z  += __shfl_down(z, o);
            dm += __shfl_down(dm, o);
        }
        if (tid == 0) sInv = 1.0f / (dm + 1e-12f * z);
    }

    // rows of b: 128 partial blocks; thread sums rows sg, sg+16, ..., sg+112
    const float4* pp = (const float4*)partial + (size_t)(b * 128) * 128 + dc * 16 + dl;
    float4 a0 = make_float4(0,0,0,0), a1 = a0, a2 = a0, a3 = a0;
    #pragma unroll
    for (int i = 0; i < 8; i += 4) {
        float4 p0 = pp[(size_t)(sg + (i + 0) * 16) * 128];
        float4 p1 = pp[(size_t)(sg + (i + 1) * 16) * 128];
        float4 p2 = pp[(size_t)(sg + (i + 2) * 16) * 128];
        float4 p3 = pp[(size_t)(sg + (i + 3) * 16) * 128];
        a0.x += p0.x; a0.y += p0.y; a0.z += p0.z; a0.w += p0.w;
        a1.x += p1.x; a1.y += p1.y; a1.z += p1.z; a1.w += p1.w;
        a2.x += p2.x; a2.y += p2.y; a2.z += p2.z; a2.w += p2.w;
        a3.x += p3.x; a3.y += p3.y; a3.z += p3.z; a3.w += p3.w;
    }
    float4 a;
    a.x = (a0.x + a1.x) + (a2.x + a3.x);
    a.y = (a0.y + a1.y) + (a2.y + a3.y);
    a.z = (a0.z + a1.z) + (a2.z + a3.z);
    a.w = (a0.w + a1.w) + (a2.w + a3.w);
    red[tid] = a;
    __syncthreads();

    #pragma unroll
    for (int h = 8; h >= 1; h >>= 1) {
        if (sg < h) {
            float4 p = red[(sg + h) * 16 + dl];
            float4 q = red[tid];
            q.x += p.x; q.y += p.y; q.z += p.z; q.w += p.w;
            red[tid] = q;
        }
        __syncthreads();
    }
    if (tid < 16) {
        const float inv = sInv;
        float4 r = red[tid];
        r.x *= inv; r.y *= inv; r.z *= inv; r.w *= inv;
        ((float4*)out)[b * 128 + dc * 16 + tid] = r;
    }
}

extern "C" void kernel_launch(void* const* d_in, const int* in_sizes, int n_in,
                              void* d_out, int out_size, void* d_ws, size_t ws_size,
                              hipStream_t stream) {
    const float* inp  = (const float*)d_in[0];
    const int*   mask = (const int*)d_in[1];
    const float* proj = (const float*)d_in[2];
    const float* hid  = (const float*)d_in[3];   // [1][32][32]
    const float* ev   = (const float*)d_in[4];   // [32]
    float* out = (float*)d_out;

    unsigned short* PTbf = (unsigned short*)d_ws;
    float2* zdm     = (float2*)((char*)d_ws + 32768);
    float*  partial = (float*)((char*)d_ws + 65536);

    kTransposeBf<<<64, 256, 0, stream>>>(proj, PTbf);
    kFused      <<<BS_ / 16, 128, 0, stream>>>(inp, mask, PTbf, hid, ev, partial, zdm);
    kReduce     <<<B_ * 8, 256, 0, stream>>>(partial, zdm, out);
}